// Round 9
// baseline (201.596 us; speedup 1.0000x reference)
//
#include <hip/hip_runtime.h>

#define EPS 1e-5f
#define B 16
#define CH 22
#define CH2 24            // padded channel count (rows 22,23 zero)
#define T_IN 1001
#define F 36
#define RF 65
#define T1 937            // T_IN - RF + 1
#define UN 885            // valid u range for A
#define PSP 944           // padded pooled-row length (need 938)
#define KS 15
#define GN 295
#define WN 129
#define M43 43
#define BF 576            // B*F
#define FLAT 1548         // F*43
#define NZ 8              // K-split factor across blocks (ch trios)

// workspace float offsets
#define P_OFF   0                 // P[bf][944]:   576*944  =   543,744
#define A_OFF   543744            // A[bf][u]:     576*885  =   509,760 -> 1,053,504
#define H2P_OFF 1053504           // h2p[8][bf][t]: 8*576*937 = 4,313,376 -> 5,366,880
#define WTT_OFF 5366880           // wtT[k][fi]:   65*36    =     2,340 -> 5,369,220
#define WST_OFF 5369220           // wsTp:         36*24*36 =    31,104 -> 5,400,324
#define WCQ_OFF 5400324           // wcQ:          12*36*60 =    25,920 -> 5,426,244
#define BN_OFF  5426244           // bnz:          6*36     =       216 -> 5,426,460

__device__ __forceinline__ float elu_f(float v) {
    return v > 0.f ? v : (__expf(v) - 1.f);
}

// ---- prep: transpose/pack weights + bn scale/offset + init out with bias ---
__global__ __launch_bounds__(256) void k_prep(
    const float* __restrict__ w_t, const float* __restrict__ w_s,
    const float* __restrict__ w_c,
    const float* __restrict__ b_t, const float* __restrict__ g_t,
    const float* __restrict__ be_t,const float* __restrict__ m_t,
    const float* __restrict__ v_t,
    const float* __restrict__ b_s, const float* __restrict__ g_s,
    const float* __restrict__ be_s,const float* __restrict__ m_s,
    const float* __restrict__ v_s,
    const float* __restrict__ b_c, const float* __restrict__ g_c,
    const float* __restrict__ be_c,const float* __restrict__ m_c,
    const float* __restrict__ v_c, const float* __restrict__ b_fc,
    float* __restrict__ wtT, float* __restrict__ wsTp,
    float* __restrict__ wcQ, float* __restrict__ bnz,
    float* __restrict__ out)
{
    int i = blockIdx.x * 256 + threadIdx.x;
    if (i < F * RF)     { int k = i / F,  fi = i % F; wtT[i] = w_t[fi * RF + k]; }
    if (i < F * CH2 * F) {            // wsTp[(fi*24+ch)*F+fo], pad ch>=22 with 0
        int fi = i / (CH2 * F);
        int r  = i % (CH2 * F);
        int ch = r / F, fo = r % F;
        wsTp[i] = (ch < CH) ? w_s[(fo * F + fi) * CH + ch] : 0.f;
    }
    if (i < 12 * 36 * 15 * 4) {       // wcQ[t3][f][k][j] = w_c[3*t3+j][f][k]
        int t3 = i / (36 * 15 * 4);
        int r  = i % (36 * 15 * 4);
        int f  = r / 60;
        int r2 = r % 60;
        int k  = r2 / 4, j = r2 % 4;
        wcQ[i] = (j < 3) ? w_c[((3 * t3 + j) * F + f) * KS + k] : 0.f;
    }
    if (i < F) {
        float s1 = g_t[i] * rsqrtf(v_t[i] + EPS);
        bnz[i]          = s1;
        bnz[F + i]      = (b_t[i] - m_t[i]) * s1 + be_t[i];
        float s2 = g_s[i] * rsqrtf(v_s[i] + EPS);
        bnz[2 * F + i]  = s2;
        bnz[3 * F + i]  = (b_s[i] - m_s[i]) * s2 + be_s[i];
        float s3 = g_c[i] * rsqrtf(v_c[i] + EPS);
        bnz[4 * F + i]  = s3;
        bnz[5 * F + i]  = (b_c[i] - m_c[i]) * s3 + be_c[i];
    }
    if (i < B * 4) out[i] = b_fc[i & 3];
}

// ---- K1: FUSED tconv + bn_t + elu + sconv -> RAW partials h2p[z][bf][t] ----
// v9: v6's per-wave shape (acc[36]+h1a[9], 52 VGPR, proven no-spill) but the
// ch axis split 8 ways ACROSS BLOCKS: grid (15, B, 8) = 1920 blocks x 256 thr
// (4 waves = 4 fi-groups x this block's ch-trio). 7680 waves = 7.5/SIMD avg
// (v6: 3.75) -> SMEM-drain stalls (the 2.3x slack at VALUBusy 30%) get 2x
// coverage. Block sums its 4 fi-group partials via a tiny LDS tree and writes
// RAW h2p (bn_s+elu deferred to k_hpool after the 8-way z sum).
// LDS 24.6 KB -> 6 blocks/CU. Extra traffic: 17.3 MB partial writes (~3 us).
__global__ __launch_bounds__(256) void k_fused(
    const float* __restrict__ x, const float* __restrict__ wtT,
    const float* __restrict__ wsTp, const float* __restrict__ bnz,
    float* __restrict__ h2p)
{
    __shared__ float xs[3 * 128];         //  1.5 KB
    __shared__ float comb[2][64][F];      // 18.4 KB
    const int tid  = threadIdx.x;
    const int lane = tid & 63;
    const int w = __builtin_amdgcn_readfirstlane(tid >> 6);  // 0..3 = fi group
    const int b  = blockIdx.y;
    const int z  = blockIdx.z;            // ch trio of CH2=24
    const int t0 = blockIdx.x * 64;
    const int ch0 = z * 3;
    const int fi0 = w * 9;

    // stage x trio [3 ch][128 t] (pad ch>=22 with 0; clamp t; garbage only
    // feeds t>=T1 lanes which are write-guarded)
    for (int i = tid; i < 3 * 128; i += 256) {
        int c = i >> 7, j = i & 127;
        int ch = ch0 + c;
        int t = t0 + j; if (t > T_IN - 1) t = T_IN - 1;
        xs[i] = (ch < CH) ? x[(b * CH + ch) * T_IN + t] : 0.f;
    }
    __syncthreads();

    float acc[F];
    #pragma unroll
    for (int fo = 0; fo < F; ++fo) acc[fo] = 0.f;

    for (int c = 0; c < 3; ++c) {
        const float* xr = xs + c * 128 + lane;

        float h1a[9];
        #pragma unroll
        for (int j = 0; j < 9; ++j) h1a[j] = 0.f;

        #pragma unroll 8
        for (int kp = 0; kp < 32; ++kp) {
            const int k = 2 * kp;
            float xv0 = xr[k];                    // adjacent dword offsets ->
            float xv1 = xr[k + 1];                //   ds_read2_b32 merge
            const float* w0 = wtT + k * F + fi0;  // wave-uniform -> s_load
            const float* w1 = w0 + F;
            #pragma unroll
            for (int j = 0; j < 9; ++j) {
                h1a[j] += xv0 * w0[j];
                h1a[j] += xv1 * w1[j];
            }
        }
        {   // tail k = 64
            float xv = xr[64];
            const float* w64 = wtT + 64 * F + fi0;
            #pragma unroll
            for (int j = 0; j < 9; ++j) h1a[j] += xv * w64[j];
        }

        // bn_t + elu in-register (bnz wave-uniform -> SGPR)
        #pragma unroll
        for (int j = 0; j < 9; ++j)
            h1a[j] = elu_f(h1a[j] * bnz[fi0 + j] + bnz[F + fi0 + j]);

        // sconv fold: acc[fo] += h1a[j] * wsTp[(fi0+j)*24 + ch0+c][fo]
        // (pad-ch rows of wsTp are zero -> garbage h1a contributes 0)
        #pragma unroll
        for (int j = 0; j < 9; ++j) {
            const float* wr = wsTp + ((fi0 + j) * CH2 + ch0 + c) * F;
            float e = h1a[j];
            #pragma unroll
            for (int fo = 0; fo < F; ++fo)
                acc[fo] += e * wr[fo];
        }
    }

    // combine 4 fi-group partials -> wave 0
    if (w >= 2) {
        float4* cb = (float4*)&comb[w - 2][lane][0];
        #pragma unroll
        for (int j = 0; j < 9; ++j)
            cb[j] = make_float4(acc[4*j], acc[4*j+1], acc[4*j+2], acc[4*j+3]);
    }
    __syncthreads();
    if (w < 2) {
        const float4* cb = (const float4*)&comb[w][lane][0];
        #pragma unroll
        for (int j = 0; j < 9; ++j) {
            float4 v = cb[j];
            acc[4*j]   += v.x; acc[4*j+1] += v.y;
            acc[4*j+2] += v.z; acc[4*j+3] += v.w;
        }
    }
    __syncthreads();
    if (w == 1) {
        float4* cb = (float4*)&comb[0][lane][0];
        #pragma unroll
        for (int j = 0; j < 9; ++j)
            cb[j] = make_float4(acc[4*j], acc[4*j+1], acc[4*j+2], acc[4*j+3]);
    }
    __syncthreads();
    if (w == 0) {
        const float4* cb = (const float4*)&comb[0][lane][0];
        #pragma unroll
        for (int j = 0; j < 9; ++j) {
            float4 v = cb[j];
            acc[4*j]   += v.x; acc[4*j+1] += v.y;
            acc[4*j+2] += v.z; acc[4*j+3] += v.w;
        }
        int t = t0 + lane;
        if (t < T1) {
            #pragma unroll
            for (int fo = 0; fo < F; ++fo)
                h2p[((size_t)(z * BF + b * F + fo)) * T1 + t] = acc[fo];
        }
    }
}

// ---- K2: combine z partials + bn_s + elu + pool3 -> P[bf][944] -------------
// h2 itself never materializes: sum 8 raw partials, bn_s+elu into LDS row,
// pool from LDS. Reads 17.3 MB, writes 2.2 MB (~3 us at HBM).
__global__ __launch_bounds__(256) void k_hpool(
    const float* __restrict__ h2p, const float* __restrict__ bnz,
    float* __restrict__ P)
{
    __shared__ float Ls[T1];              // 3.7 KB
    const int bf = blockIdx.x;
    const int f = bf % F;
    const float s2 = bnz[2 * F + f], o2 = bnz[3 * F + f];
    for (int i = threadIdx.x; i < T1; i += 256) {
        float s = 0.f;
        #pragma unroll
        for (int z = 0; z < NZ; ++z)
            s += h2p[((size_t)(z * BF + bf)) * T1 + i];
        Ls[i] = elu_f(s * s2 + o2);
    }
    __syncthreads();
    float* Pr = P + (size_t)bf * PSP;
    for (int i = threadIdx.x; i < PSP; i += 256) {
        int s0 = i     < T1 - 1 ? i     : T1 - 1;
        int s1 = i + 1 < T1 - 1 ? i + 1 : T1 - 1;
        int s2i= i + 2 < T1 - 1 ? i + 2 : T1 - 1;
        Pr[i] = (Ls[s0] + Ls[s1] + Ls[s2i]) * (1.f / 3.f);
    }
}

// ---- K3: dilated conv + bn_c + elu -> A[bf][u]  (pipe-separated) -----------
// Wave = one fo-triple (12 waves cover 36 fo); full 36f x 15k reduction into
// acc[3]/thread. P via VMEM (vmcnt), wcQ via wide s_loads (lgkm, DS-free).
__global__ __launch_bounds__(768) void k_qconv(
    const float* __restrict__ P, const float* __restrict__ wcQ,
    const float* __restrict__ bnz, float* __restrict__ A)
{
    const int tid  = threadIdx.x;
    const int lane = tid & 63;
    const int t3 = __builtin_amdgcn_readfirstlane(tid >> 6);  // 0..11
    const int b  = blockIdx.y;
    const int u0 = blockIdx.x * 64;
    const int fo0 = t3 * 3;

    const float* wq = wcQ + t3 * (36 * 60);

    float a0 = 0.f, a1 = 0.f, a2 = 0.f;

    for (int f = 0; f < F; ++f) {
        const float* Pr = P + (size_t)(b * F + f) * PSP + u0 + lane;
        const float* wf = wq + f * 60;            // wave-uniform, 60 consec
        #pragma unroll
        for (int k = 0; k < KS; ++k) {
            float pv = Pr[3 * k];                 // VMEM, imm offset 12*k
            a0 += pv * wf[4 * k + 0];
            a1 += pv * wf[4 * k + 1];
            a2 += pv * wf[4 * k + 2];
        }
    }

    int u = u0 + lane;
    if (u < UN) {
        float sc0 = bnz[4 * F + fo0 + 0], oc0 = bnz[5 * F + fo0 + 0];
        float sc1 = bnz[4 * F + fo0 + 1], oc1 = bnz[5 * F + fo0 + 1];
        float sc2 = bnz[4 * F + fo0 + 2], oc2 = bnz[5 * F + fo0 + 2];
        A[((size_t)(b * F + fo0 + 0)) * UN + u] = elu_f(a0 * sc0 + oc0);
        A[((size_t)(b * F + fo0 + 1)) * UN + u] = elu_f(a1 * sc1 + oc1);
        A[((size_t)(b * F + fo0 + 2)) * UN + u] = elu_f(a2 * sc2 + oc2);
    }
}

// ---- K4: window sums over finished A + fused FC -> atomicAdd out -----------
__global__ __launch_bounds__(256) void k_wins(
    const float* __restrict__ A, const float* __restrict__ w_fc,
    float* __restrict__ out)
{
    __shared__ float Es[UN];
    __shared__ float G[GN];
    __shared__ float Ws[WN];
    __shared__ float Sm[M43];
    const int tid = threadIdx.x;
    const int bf = blockIdx.x;
    const int b = bf / F, f = bf % F;
    for (int i = tid; i < UN; i += 256)
        Es[i] = A[(size_t)bf * UN + i];
    __syncthreads();
    for (int q = tid; q < GN; q += 256)
        G[q] = Es[3 * q] + Es[3 * q + 1] + Es[3 * q + 2];
    __syncthreads();
    if (tid < WN) {
        float a = 0.f;
        for (int q = tid; q < tid + 167; ++q) a += G[q];
        Ws[tid] = a;
    }
    __syncthreads();
    if (tid < M43)
        Sm[tid] = (Ws[3 * tid] + Ws[3 * tid + 1] + Ws[3 * tid + 2]) * (1.f / 3.f);
    __syncthreads();
    if (tid < 4) {
        const float* wr = w_fc + tid * FLAT + f * M43;
        float a = 0.f;
        #pragma unroll 43
        for (int m = 0; m < M43; ++m) a += Sm[m] * wr[m];
        atomicAdd(&out[b * 4 + tid], a * (1.f / 501.f));
    }
}

extern "C" void kernel_launch(void* const* d_in, const int* in_sizes, int n_in,
                              void* d_out, int out_size, void* d_ws, size_t ws_size,
                              hipStream_t stream) {
    const float* x    = (const float*)d_in[0];
    const float* w_t  = (const float*)d_in[1];
    const float* b_t  = (const float*)d_in[2];
    const float* g_t  = (const float*)d_in[3];
    const float* be_t = (const float*)d_in[4];
    const float* m_t  = (const float*)d_in[5];
    const float* v_t  = (const float*)d_in[6];
    const float* w_s  = (const float*)d_in[7];
    const float* b_s  = (const float*)d_in[8];
    const float* g_s  = (const float*)d_in[9];
    const float* be_s = (const float*)d_in[10];
    const float* m_s  = (const float*)d_in[11];
    const float* v_s  = (const float*)d_in[12];
    const float* w_c  = (const float*)d_in[13];
    const float* b_c  = (const float*)d_in[14];
    const float* g_c  = (const float*)d_in[15];
    const float* be_c = (const float*)d_in[16];
    const float* m_c  = (const float*)d_in[17];
    const float* v_c  = (const float*)d_in[18];
    const float* w_fc = (const float*)d_in[19];
    const float* b_fc = (const float*)d_in[20];

    float* ws   = (float*)d_ws;
    float* P    = ws + P_OFF;
    float* A    = ws + A_OFF;
    float* h2p  = ws + H2P_OFF;
    float* wtT  = ws + WTT_OFF;
    float* wsTp = ws + WST_OFF;
    float* wcQ  = ws + WCQ_OFF;
    float* bnz  = ws + BN_OFF;
    float* out  = (float*)d_out;

    k_prep<<<dim3(128), 256, 0, stream>>>(
        w_t, w_s, w_c, b_t, g_t, be_t, m_t, v_t,
        b_s, g_s, be_s, m_s, v_s, b_c, g_c, be_c, m_c, v_c, b_fc,
        wtT, wsTp, wcQ, bnz, out);

    k_fused<<<dim3(15, B, NZ), 256, 0, stream>>>(x, wtT, wsTp, bnz, h2p);
    k_hpool<<<dim3(BF), 256, 0, stream>>>(h2p, bnz, P);
    k_qconv<<<dim3(14, B), 768, 0, stream>>>(P, wcQ, bnz, A);
    k_wins<<<dim3(BF), 256, 0, stream>>>(A, w_fc, out);
}

// Round 10
// 197.014 us; speedup vs baseline: 1.0233x; 1.0233x over previous
//
#include <hip/hip_runtime.h>

#define EPS 1e-5f
#define B 16
#define CH 22
#define CH2 24            // padded channel count (rows 22,23 zero)
#define T_IN 1001
#define F 36
#define RF 65
#define T1 937            // T_IN - RF + 1
#define UN 885            // valid u range for A
#define PSP 944           // padded pooled-row length (need 938)
#define KS 15
#define GN 295
#define WN 129
#define M43 43
#define BF 576            // B*F
#define FLAT 1548         // F*43
#define NZ 8              // K-split factor across blocks (ch trios)

// workspace float offsets
#define P_OFF   0                 // P[bf][944]:   576*944  =   543,744
#define A_OFF   543744            // A[bf][u]:     576*885  =   509,760 -> 1,053,504
#define H2P_OFF 1053504           // h2p[8][bf][t]: 8*576*937 = 4,313,376 -> 5,366,880
#define WTG_OFF 5366880           // wtG[g][kp][24]: 4*33*24 =    3,168 -> 5,370,048
#define WSG_OFF 5370048           // wsG[g][z][27][36]: 4*8*27*36 = 31,104 -> 5,401,152
#define WCQ_OFF 5401152           // wcQ:          12*36*60 =    25,920 -> 5,427,072
#define BN_OFF  5427072           // bnz:          6*36     =       216 -> 5,427,288

__device__ __forceinline__ float elu_f(float v) {
    return v > 0.f ? v : (__expf(v) - 1.f);
}

// ---- prep: pack weights + bn scale/offset + init out with bias -------------
__global__ __launch_bounds__(256) void k_prep(
    const float* __restrict__ w_t, const float* __restrict__ w_s,
    const float* __restrict__ w_c,
    const float* __restrict__ b_t, const float* __restrict__ g_t,
    const float* __restrict__ be_t,const float* __restrict__ m_t,
    const float* __restrict__ v_t,
    const float* __restrict__ b_s, const float* __restrict__ g_s,
    const float* __restrict__ be_s,const float* __restrict__ m_s,
    const float* __restrict__ v_s,
    const float* __restrict__ b_c, const float* __restrict__ g_c,
    const float* __restrict__ be_c,const float* __restrict__ m_c,
    const float* __restrict__ v_c, const float* __restrict__ b_fc,
    float* __restrict__ wtG, float* __restrict__ wsG,
    float* __restrict__ wcQ, float* __restrict__ bnz,
    float* __restrict__ out)
{
    int i = blockIdx.x * 256 + threadIdx.x;
    if (i < 4 * 33 * 24) {            // wtG[g][kp][kk*12+j] = w_t[g*9+j][2kp+kk]
        int g  = i / (33 * 24);
        int r  = i % (33 * 24);
        int kp = r / 24, slot = r % 24;
        int kk = slot / 12, j = slot % 12;
        int k  = 2 * kp + kk;
        wtG[i] = (j < 9 && k < RF) ? w_t[(g * 9 + j) * RF + k] : 0.f;
    }
    if (i < 4 * 8 * 27 * 36) {        // wsG[g][z][j*3+c][fo] = w_s[fo][g*9+j][z*3+c]
        int g  = i / (8 * 27 * 36);
        int r  = i % (8 * 27 * 36);
        int z  = r / (27 * 36);
        int r2 = r % (27 * 36);
        int jc = r2 / 36, fo = r2 % 36;
        int j  = jc / 3, c = jc % 3;
        int fi = g * 9 + j, ch = z * 3 + c;
        wsG[i] = (ch < CH) ? w_s[(fo * F + fi) * CH + ch] : 0.f;
    }
    if (i < 12 * 36 * 15 * 4) {       // wcQ[t3][f][k][j] = w_c[3*t3+j][f][k]
        int t3 = i / (36 * 15 * 4);
        int r  = i % (36 * 15 * 4);
        int f  = r / 60;
        int r2 = r % 60;
        int k  = r2 / 4, j = r2 % 4;
        wcQ[i] = (j < 3) ? w_c[((3 * t3 + j) * F + f) * KS + k] : 0.f;
    }
    if (i < F) {
        float s1 = g_t[i] * rsqrtf(v_t[i] + EPS);
        bnz[i]          = s1;
        bnz[F + i]      = (b_t[i] - m_t[i]) * s1 + be_t[i];
        float s2 = g_s[i] * rsqrtf(v_s[i] + EPS);
        bnz[2 * F + i]  = s2;
        bnz[3 * F + i]  = (b_s[i] - m_s[i]) * s2 + be_s[i];
        float s3 = g_c[i] * rsqrtf(v_c[i] + EPS);
        bnz[4 * F + i]  = s3;
        bnz[5 * F + i]  = (b_c[i] - m_c[i]) * s3 + be_c[i];
    }
    if (i < B * 4) out[i] = b_fc[i & 3];
}

// ---- K1: FUSED tconv + bn_t + elu + sconv -> RAW partials h2p[z][bf][t] ----
// v10: v9's duration was INVARIANT (69.5 us across 3 structures) because the
// total SMEM request count was invariant: weight s_loads sat inside the
// c-loop, so each wave re-fetched its 65-row weight stream per channel, and
// wsTp streaming thrashed the 16KB SQC. Fix: kp-OUTER / c-INNER — fetch the
// 24-float wtG row ONCE per k-pair (2 s_loads), apply to all 3 channels
// (108 FMA); sconv weights as one contiguous sequential 3.9KB stream (wsG).
// Per-wave requests ~290 -> ~160; total ~2.5M -> ~1.2M, sequential locality.
// 256 thr (compiler allocates honestly at this size: v9 = 48 VGPR no spill);
// live state h1a[27]+acc[36] ~ 80 VGPR. grid (15, B, 8) = 1920 blocks.
__global__ __launch_bounds__(256, 4) void k_fused(
    const float* __restrict__ x, const float* __restrict__ wtG,
    const float* __restrict__ wsG, const float* __restrict__ bnz,
    float* __restrict__ h2p)
{
    __shared__ float xs[3 * 128];         //  1.5 KB
    __shared__ float comb[2][64][F];      // 18.4 KB
    const int tid  = threadIdx.x;
    const int lane = tid & 63;
    const int w = __builtin_amdgcn_readfirstlane(tid >> 6);  // 0..3 = fi group
    const int b  = blockIdx.y;
    const int z  = blockIdx.z;            // ch trio of CH2=24
    const int t0 = blockIdx.x * 64;
    const int ch0 = z * 3;
    const int fi0 = w * 9;

    // stage x trio [3 ch][128 t] (pad ch>=22 with 0; clamp t; garbage only
    // feeds t>=T1 lanes which are write-guarded)
    for (int i = tid; i < 3 * 128; i += 256) {
        int c = i >> 7, j = i & 127;
        int ch = ch0 + c;
        int t = t0 + j; if (t > T_IN - 1) t = T_IN - 1;
        xs[i] = (ch < CH) ? x[(b * CH + ch) * T_IN + t] : 0.f;
    }
    __syncthreads();

    const float* wgB = wtG + w * (33 * 24);

    float h1a[3][9];
    #pragma unroll
    for (int c = 0; c < 3; ++c)
        #pragma unroll
        for (int j = 0; j < 9; ++j) h1a[c][j] = 0.f;

    // kp-outer: one 24-float uniform weight fetch feeds 3 channels x 2 k.
    #pragma unroll 8
    for (int kp = 0; kp < 32; ++kp) {
        const float* wp = wgB + kp * 24;          // wave-uniform, contiguous
        #pragma unroll
        for (int c = 0; c < 3; ++c) {
            float xv0 = xs[c * 128 + lane + 2 * kp];      // ds_read2 pair
            float xv1 = xs[c * 128 + lane + 2 * kp + 1];
            #pragma unroll
            for (int j = 0; j < 9; ++j)
                h1a[c][j] += xv0 * wp[j] + xv1 * wp[12 + j];
        }
    }
    {   // tail k = 64 (kp = 32, kk = 0 slots)
        const float* wp = wgB + 32 * 24;
        #pragma unroll
        for (int c = 0; c < 3; ++c) {
            float xv = xs[c * 128 + lane + 64];
            #pragma unroll
            for (int j = 0; j < 9; ++j) h1a[c][j] += xv * wp[j];
        }
    }

    // bn_t + elu in-register (bnz wave-uniform -> SGPR)
    #pragma unroll
    for (int j = 0; j < 9; ++j) {
        float s1 = bnz[fi0 + j], o1 = bnz[F + fi0 + j];
        #pragma unroll
        for (int c = 0; c < 3; ++c)
            h1a[c][j] = elu_f(h1a[c][j] * s1 + o1);
    }

    // sconv fold: sequential 27x36 weight stream for this (g,z)
    float acc[F];
    #pragma unroll
    for (int fo = 0; fo < F; ++fo) acc[fo] = 0.f;

    const float* wsB = wsG + (w * NZ + z) * (27 * 36);
    #pragma unroll
    for (int j = 0; j < 9; ++j) {
        #pragma unroll
        for (int c = 0; c < 3; ++c) {
            const float* wr = wsB + (j * 3 + c) * 36;   // 144B contiguous
            float e = h1a[c][j];
            #pragma unroll
            for (int fo = 0; fo < F; ++fo)
                acc[fo] += e * wr[fo];
        }
    }

    // combine 4 fi-group partials -> wave 0
    if (w >= 2) {
        float4* cb = (float4*)&comb[w - 2][lane][0];
        #pragma unroll
        for (int j = 0; j < 9; ++j)
            cb[j] = make_float4(acc[4*j], acc[4*j+1], acc[4*j+2], acc[4*j+3]);
    }
    __syncthreads();
    if (w < 2) {
        const float4* cb = (const float4*)&comb[w][lane][0];
        #pragma unroll
        for (int j = 0; j < 9; ++j) {
            float4 v = cb[j];
            acc[4*j]   += v.x; acc[4*j+1] += v.y;
            acc[4*j+2] += v.z; acc[4*j+3] += v.w;
        }
    }
    __syncthreads();
    if (w == 1) {
        float4* cb = (float4*)&comb[0][lane][0];
        #pragma unroll
        for (int j = 0; j < 9; ++j)
            cb[j] = make_float4(acc[4*j], acc[4*j+1], acc[4*j+2], acc[4*j+3]);
    }
    __syncthreads();
    if (w == 0) {
        const float4* cb = (const float4*)&comb[0][lane][0];
        #pragma unroll
        for (int j = 0; j < 9; ++j) {
            float4 v = cb[j];
            acc[4*j]   += v.x; acc[4*j+1] += v.y;
            acc[4*j+2] += v.z; acc[4*j+3] += v.w;
        }
        int t = t0 + lane;
        if (t < T1) {
            #pragma unroll
            for (int fo = 0; fo < F; ++fo)
                h2p[((size_t)(z * BF + b * F + fo)) * T1 + t] = acc[fo];
        }
    }
}

// ---- K2: combine z partials + bn_s + elu + pool3 -> P[bf][944] -------------
__global__ __launch_bounds__(256) void k_hpool(
    const float* __restrict__ h2p, const float* __restrict__ bnz,
    float* __restrict__ P)
{
    __shared__ float Ls[T1];              // 3.7 KB
    const int bf = blockIdx.x;
    const int f = bf % F;
    const float s2 = bnz[2 * F + f], o2 = bnz[3 * F + f];
    for (int i = threadIdx.x; i < T1; i += 256) {
        float s = 0.f;
        #pragma unroll
        for (int z = 0; z < NZ; ++z)
            s += h2p[((size_t)(z * BF + bf)) * T1 + i];
        Ls[i] = elu_f(s * s2 + o2);
    }
    __syncthreads();
    float* Pr = P + (size_t)bf * PSP;
    for (int i = threadIdx.x; i < PSP; i += 256) {
        int s0 = i     < T1 - 1 ? i     : T1 - 1;
        int s1 = i + 1 < T1 - 1 ? i + 1 : T1 - 1;
        int s2i= i + 2 < T1 - 1 ? i + 2 : T1 - 1;
        Pr[i] = (Ls[s0] + Ls[s1] + Ls[s2i]) * (1.f / 3.f);
    }
}

// ---- K3: dilated conv + bn_c + elu -> A[bf][u]  (pipe-separated) -----------
__global__ __launch_bounds__(768) void k_qconv(
    const float* __restrict__ P, const float* __restrict__ wcQ,
    const float* __restrict__ bnz, float* __restrict__ A)
{
    const int tid  = threadIdx.x;
    const int lane = tid & 63;
    const int t3 = __builtin_amdgcn_readfirstlane(tid >> 6);  // 0..11
    const int b  = blockIdx.y;
    const int u0 = blockIdx.x * 64;
    const int fo0 = t3 * 3;

    const float* wq = wcQ + t3 * (36 * 60);

    float a0 = 0.f, a1 = 0.f, a2 = 0.f;

    for (int f = 0; f < F; ++f) {
        const float* Pr = P + (size_t)(b * F + f) * PSP + u0 + lane;
        const float* wf = wq + f * 60;            // wave-uniform, 60 consec
        #pragma unroll
        for (int k = 0; k < KS; ++k) {
            float pv = Pr[3 * k];                 // VMEM, imm offset 12*k
            a0 += pv * wf[4 * k + 0];
            a1 += pv * wf[4 * k + 1];
            a2 += pv * wf[4 * k + 2];
        }
    }

    int u = u0 + lane;
    if (u < UN) {
        float sc0 = bnz[4 * F + fo0 + 0], oc0 = bnz[5 * F + fo0 + 0];
        float sc1 = bnz[4 * F + fo0 + 1], oc1 = bnz[5 * F + fo0 + 1];
        float sc2 = bnz[4 * F + fo0 + 2], oc2 = bnz[5 * F + fo0 + 2];
        A[((size_t)(b * F + fo0 + 0)) * UN + u] = elu_f(a0 * sc0 + oc0);
        A[((size_t)(b * F + fo0 + 1)) * UN + u] = elu_f(a1 * sc1 + oc1);
        A[((size_t)(b * F + fo0 + 2)) * UN + u] = elu_f(a2 * sc2 + oc2);
    }
}

// ---- K4: window sums over finished A + fused FC -> atomicAdd out -----------
__global__ __launch_bounds__(256) void k_wins(
    const float* __restrict__ A, const float* __restrict__ w_fc,
    float* __restrict__ out)
{
    __shared__ float Es[UN];
    __shared__ float G[GN];
    __shared__ float Ws[WN];
    __shared__ float Sm[M43];
    const int tid = threadIdx.x;
    const int bf = blockIdx.x;
    const int b = bf / F, f = bf % F;
    for (int i = tid; i < UN; i += 256)
        Es[i] = A[(size_t)bf * UN + i];
    __syncthreads();
    for (int q = tid; q < GN; q += 256)
        G[q] = Es[3 * q] + Es[3 * q + 1] + Es[3 * q + 2];
    __syncthreads();
    if (tid < WN) {
        float a = 0.f;
        for (int q = tid; q < tid + 167; ++q) a += G[q];
        Ws[tid] = a;
    }
    __syncthreads();
    if (tid < M43)
        Sm[tid] = (Ws[3 * tid] + Ws[3 * tid + 1] + Ws[3 * tid + 2]) * (1.f / 3.f);
    __syncthreads();
    if (tid < 4) {
        const float* wr = w_fc + tid * FLAT + f * M43;
        float a = 0.f;
        #pragma unroll 43
        for (int m = 0; m < M43; ++m) a += Sm[m] * wr[m];
        atomicAdd(&out[b * 4 + tid], a * (1.f / 501.f));
    }
}

extern "C" void kernel_launch(void* const* d_in, const int* in_sizes, int n_in,
                              void* d_out, int out_size, void* d_ws, size_t ws_size,
                              hipStream_t stream) {
    const float* x    = (const float*)d_in[0];
    const float* w_t  = (const float*)d_in[1];
    const float* b_t  = (const float*)d_in[2];
    const float* g_t  = (const float*)d_in[3];
    const float* be_t = (const float*)d_in[4];
    const float* m_t  = (const float*)d_in[5];
    const float* v_t  = (const float*)d_in[6];
    const float* w_s  = (const float*)d_in[7];
    const float* b_s  = (const float*)d_in[8];
    const float* g_s  = (const float*)d_in[9];
    const float* be_s = (const float*)d_in[10];
    const float* m_s  = (const float*)d_in[11];
    const float* v_s  = (const float*)d_in[12];
    const float* w_c  = (const float*)d_in[13];
    const float* b_c  = (const float*)d_in[14];
    const float* g_c  = (const float*)d_in[15];
    const float* be_c = (const float*)d_in[16];
    const float* m_c  = (const float*)d_in[17];
    const float* v_c  = (const float*)d_in[18];
    const float* w_fc = (const float*)d_in[19];
    const float* b_fc = (const float*)d_in[20];

    float* ws   = (float*)d_ws;
    float* P    = ws + P_OFF;
    float* A    = ws + A_OFF;
    float* h2p  = ws + H2P_OFF;
    float* wtG  = ws + WTG_OFF;
    float* wsG  = ws + WSG_OFF;
    float* wcQ  = ws + WCQ_OFF;
    float* bnz  = ws + BN_OFF;
    float* out  = (float*)d_out;

    k_prep<<<dim3(128), 256, 0, stream>>>(
        w_t, w_s, w_c, b_t, g_t, be_t, m_t, v_t,
        b_s, g_s, be_s, m_s, v_s, b_c, g_c, be_c, m_c, v_c, b_fc,
        wtG, wsG, wcQ, bnz, out);

    k_fused<<<dim3(15, B, NZ), 256, 0, stream>>>(x, wtG, wsG, bnz, h2p);
    k_hpool<<<dim3(BF), 256, 0, stream>>>(h2p, bnz, P);
    k_qconv<<<dim3(14, B), 768, 0, stream>>>(P, wcQ, bnz, A);
    k_wins<<<dim3(BF), 256, 0, stream>>>(A, w_fc, out);
}